// Round 1
// baseline (723.115 us; speedup 1.0000x reference)
//
#include <hip/hip_runtime.h>

// DiffSSM: B=8, L=2048, D=1024, N=64
#define Bq 8
#define Lq 2048
#define Dq 1024
#define LPq 2050  // L + 2 pad rows

typedef unsigned short u16;
typedef __attribute__((ext_vector_type(8))) short bf16x8;
typedef __attribute__((ext_vector_type(4))) float f32x4;

__device__ __forceinline__ u16 f2bf(float f) {
  unsigned u = __float_as_uint(f);
  u += 0x7FFFu + ((u >> 16) & 1u);   // RNE
  return (u16)(u >> 16);
}
__device__ __forceinline__ float bf2f(u16 s) {
  return __uint_as_float(((unsigned)s) << 16);
}
__device__ __forceinline__ void gld16(const u16* g, u16* l) {
  __builtin_amdgcn_global_load_lds((const __attribute__((address_space(1))) void*)g,
                                   (__attribute__((address_space(3))) void*)l, 16, 0, 0);
}

// ---------------- prep kernels ----------------

// blocks 0-7: kf/kb (2048); blocks 8-39: c1/c2 (8192); blocks 40-167: zero pads (32768)
__global__ __launch_bounds__(256) void prep_small(
    const float* __restrict__ t, const float* __restrict__ beta1, const float* __restrict__ beta2,
    const float* __restrict__ Af, const float* __restrict__ Bf, const float* __restrict__ Cf, const float* __restrict__ Df,
    const float* __restrict__ Ab, const float* __restrict__ Bb, const float* __restrict__ Cb, const float* __restrict__ Db,
    float* __restrict__ kf, float* __restrict__ kb,
    float* __restrict__ c1, float* __restrict__ c2,
    u16* __restrict__ hpad, u16* __restrict__ copad) {
  int tid = blockIdx.x * 256 + threadIdx.x;
  if (blockIdx.x < 8) {
    int l = tid;
    float sf = Df[0], sb = Db[0];
    for (int n = 0; n < 64; n++) {
      sf += __expf((float)l * Af[n * 64 + n]) * (Bf[n] * Cf[n]);
      sb += __expf((float)l * Ab[n * 64 + n]) * (Bb[n] * Cb[n]);
    }
    kf[l] = sf; kb[l] = sb;
  } else if (blockIdx.x < 40) {
    int i = tid - 2048;                 // [0, 8192)
    int b = i >> 10, d = i & 1023;
    float tb = t[b];
    float e;
    if (d < 512) {
      float f = __expf((float)d * (-logf(10000.f) / 511.f));
      e = sinf(tb * f);
    } else {
      float f = __expf((float)(d - 512) * (-logf(10000.f) / 511.f));
      e = cosf(tb * f);
    }
    float ns = 1.f / (1.f + __expf(-e));
    c1[i] = beta1[0] * ns;
    c2[i] = beta2[0] * ns;
  } else {
    int i = tid - 10240;                // [0, 32768)
    if (i < 32768) {
      int d = i & 1023;
      int j = i >> 10;                  // [0,32)
      int arr = j & 1, r = (j >> 1) & 1, b = j >> 2;
      size_t off = (size_t)b * LPq * Dq + (r ? (size_t)(LPq - 1) * Dq : 0) + d;
      if (arr == 0) hpad[off] = 0;
      else          copad[off] = 0;
    }
  }
}

__global__ __launch_bounds__(256) void cast_x(const float* __restrict__ x, u16* __restrict__ xb) {
  size_t i = ((size_t)blockIdx.x * 256 + threadIdx.x) * 8;
  float4 a = *(const float4*)(x + i);
  float4 b = *(const float4*)(x + i + 4);
  u16 o[8] = {f2bf(a.x), f2bf(a.y), f2bf(a.z), f2bf(a.w),
              f2bf(b.x), f2bf(b.y), f2bf(b.z), f2bf(b.w)};
  *(bf16x8*)(xb + i) = *(const bf16x8*)o;
}

// W (K=1024 x N=1024) row-major -> Wt (N x K) bf16
__global__ __launch_bounds__(256) void trans_w(const float* __restrict__ W, u16* __restrict__ Wt) {
  __shared__ float tile[64][65];
  int bx = blockIdx.x & 15, by = blockIdx.x >> 4;
  int tx = threadIdx.x & 63, tw = threadIdx.x >> 6;
  for (int r = tw; r < 64; r += 4)
    tile[r][tx] = W[(size_t)(by * 64 + r) * 1024 + bx * 64 + tx];
  __syncthreads();
  for (int r = tw; r < 64; r += 4)
    Wt[(size_t)(bx * 64 + r) * 1024 + by * 64 + tx] = f2bf(tile[tx][r]);
}

// w (O,I,3) -> Wt[o][dt*1024 + i] = w[o][i][dt]  bf16
__global__ __launch_bounds__(256) void trans_w3(const float* __restrict__ w, u16* __restrict__ Wt) {
  int idx = blockIdx.x * 256 + threadIdx.x;          // [0, 3145728)
  int o = idx / 3072, rem = idx % 3072;
  int dt = rem >> 10, i = rem & 1023;
  Wt[idx] = f2bf(w[(size_t)o * 3072 + i * 3 + dt]);
}

// Tf[t][j] = t>=j ? kf[t-j] : 0 ; Tb[t][j] = j>=t ? kb[j-t] : 0
__global__ __launch_bounds__(256) void tf_fill(const float* __restrict__ kf, const float* __restrict__ kb,
                                               u16* __restrict__ Tf, u16* __restrict__ Tb) {
  int idx = blockIdx.x * 256 + threadIdx.x;          // [0, 4194304)
  int t = idx >> 11, j = idx & 2047;
  Tf[idx] = (t >= j) ? f2bf(kf[t - j]) : (u16)0;
  Tb[idx] = (j >= t) ? f2bf(kb[j - t]) : (u16)0;
}

// hpad rows 1..L (bf16, per batch) -> ht (B, D, L) bf16
__global__ __launch_bounds__(256) void trans_h(const u16* __restrict__ hpad, u16* __restrict__ ht) {
  __shared__ u16 tile[64][65];
  int b = blockIdx.z;
  int lt = blockIdx.x * 64, dt = blockIdx.y * 64;
  int tx = threadIdx.x & 63, tw = threadIdx.x >> 6;
  const u16* src = hpad + (size_t)b * LPq * Dq + (size_t)(lt + 1) * Dq + dt;
  for (int r = tw; r < 64; r += 4) tile[r][tx] = src[(size_t)r * Dq + tx];
  __syncthreads();
  u16* dst = ht + ((size_t)b * Dq + dt) * Lq + lt;
  for (int r = tw; r < 64; r += 4) dst[(size_t)r * Lq + tx] = tile[tx][r];
}

// ---------------- LayerNorm ----------------

__device__ __forceinline__ void block_reduce2(float& s, float& q) {
  for (int o = 32; o > 0; o >>= 1) { s += __shfl_xor(s, o); q += __shfl_xor(q, o); }
  __shared__ float rs[4], rq[4];
  int w = threadIdx.x >> 6, lane = threadIdx.x & 63;
  if (lane == 0) { rs[w] = s; rq[w] = q; }
  __syncthreads();
  s = rs[0] + rs[1] + rs[2] + rs[3];
  q = rq[0] + rq[1] + rq[2] + rq[3];
}

// LN over D=1024 of h0 (bf16) -> hpad rows 1..L (bf16)
__global__ __launch_bounds__(256) void ln1_k(const u16* __restrict__ h0, u16* __restrict__ hpad,
                                             const float* __restrict__ g, const float* __restrict__ be) {
  int r = blockIdx.x, tid = threadIdx.x;
  int d0 = tid * 4;
  ushort4 hv = *(const ushort4*)(h0 + (size_t)r * 1024 + d0);
  float v0 = bf2f(hv.x), v1 = bf2f(hv.y), v2 = bf2f(hv.z), v3 = bf2f(hv.w);
  float s = v0 + v1 + v2 + v3;
  float q = v0 * v0 + v1 * v1 + v2 * v2 + v3 * v3;
  block_reduce2(s, q);
  float mean = s * (1.f / 1024.f);
  float var = q * (1.f / 1024.f) - mean * mean;
  float rstd = rsqrtf(var + 1e-5f);
  int b_ = r >> 11, l = r & 2047;
  ushort4 ov;
  ov.x = f2bf((v0 - mean) * rstd * g[d0 + 0] + be[d0 + 0]);
  ov.y = f2bf((v1 - mean) * rstd * g[d0 + 1] + be[d0 + 1]);
  ov.z = f2bf((v2 - mean) * rstd * g[d0 + 2] + be[d0 + 2]);
  ov.w = f2bf((v3 - mean) * rstd * g[d0 + 3] + be[d0 + 3]);
  *(ushort4*)(hpad + ((size_t)b_ * LPq + l + 1) * Dq + d0) = ov;
}

// out = x + LN(h) (h bf16, x/out fp32)
__global__ __launch_bounds__(256) void ln2_k(const u16* __restrict__ hp, const float* __restrict__ x,
                                             const float* __restrict__ g, const float* __restrict__ be,
                                             float* __restrict__ out) {
  int r = blockIdx.x, tid = threadIdx.x;
  int d0 = tid * 4;
  size_t base = (size_t)r * 1024 + d0;
  ushort4 hv = *(const ushort4*)(hp + base);
  float v0 = bf2f(hv.x), v1 = bf2f(hv.y), v2 = bf2f(hv.z), v3 = bf2f(hv.w);
  float s = v0 + v1 + v2 + v3;
  float q = v0 * v0 + v1 * v1 + v2 * v2 + v3 * v3;
  block_reduce2(s, q);
  float mean = s * (1.f / 1024.f);
  float var = q * (1.f / 1024.f) - mean * mean;
  float rstd = rsqrtf(var + 1e-5f);
  float4 xv = *(const float4*)(x + base);
  float4 o;
  o.x = xv.x + (v0 - mean) * rstd * g[d0 + 0] + be[d0 + 0];
  o.y = xv.y + (v1 - mean) * rstd * g[d0 + 1] + be[d0 + 1];
  o.z = xv.z + (v2 - mean) * rstd * g[d0 + 2] + be[d0 + 2];
  o.w = xv.w + (v3 - mean) * rstd * g[d0 + 3] + be[d0 + 3];
  *(float4*)(out + base) = o;
}

// ---------------- MFMA GEMM (m97-style: 128x128 tile, BK=32, 4 waves) ----------------
// A: per-batch rows, row stride lda, batch stride abstr (bf16)
// Bw: weights pre-transposed (N x K, row stride ldb) (bf16)
// MODE 0: out = acc + bias            -> bf16
// MODE 1: out = silu(acc + bias)      -> bf16
// MODE 2: out = acc + bias + out_old  -> bf16   (in-place add)
template <int MODE>
__global__ __launch_bounds__(256) void gemm_k(
    const u16* __restrict__ A, long lda, long abstr,
    const u16* __restrict__ Bw, long ldb,
    u16* __restrict__ Out, long obstr,
    const float* __restrict__ bias, int K, int nbm) {
  __shared__ __align__(16) u16 As[128 * 32];
  __shared__ __align__(16) u16 Bs[128 * 32];
  int mb = blockIdx.x % nbm, nb = blockIdx.x / nbm;
  int m0 = mb * 128, n0 = nb * 128;
  int batch = m0 >> 11, r0 = m0 & 2047;
  const u16* Abase = A + (size_t)batch * abstr + (size_t)r0 * lda;
  int t = threadIdx.x;
  int rr = t >> 2, cc = (t & 3) * 8;
  const u16* ga = Abase + (size_t)rr * lda + cc;
  const u16* gb = Bw + (size_t)(n0 + rr) * ldb + cc;
  u16* la = &As[rr * 32 + cc];
  u16* lb = &Bs[rr * 32 + cc];
  int lane = t & 63, w = t >> 6;
  int wm = (w >> 1) * 64, wn = (w & 1) * 64;
  int frow = lane & 15, fk = (lane >> 4) * 8;
  const u16* pa = &As[(wm + frow) * 32 + fk];
  const u16* pb = &Bs[(wn + frow) * 32 + fk];
  f32x4 acc[4][4] = {};
  for (int k0 = 0; k0 < K; k0 += 32) {
    gld16(ga + k0, la);
    gld16(ga + k0 + (size_t)64 * lda, la + 64 * 32);
    gld16(gb + k0, lb);
    gld16(gb + k0 + (size_t)64 * ldb, lb + 64 * 32);
    asm volatile("s_waitcnt vmcnt(0)" ::: "memory");
    __syncthreads();
    bf16x8 af[4], bq[4];
#pragma unroll
    for (int i = 0; i < 4; i++) {
      af[i] = *(const bf16x8*)(pa + i * 512);
      bq[i] = *(const bf16x8*)(pb + i * 512);
    }
#pragma unroll
    for (int mi = 0; mi < 4; mi++)
#pragma unroll
      for (int ni = 0; ni < 4; ni++)
        acc[mi][ni] = __builtin_amdgcn_mfma_f32_16x16x32_bf16(af[mi], bq[ni], acc[mi][ni], 0, 0, 0);
    __syncthreads();
  }
  u16* ob = Out + (size_t)batch * obstr;
#pragma unroll
  for (int mi = 0; mi < 4; mi++) {
    int rbase = r0 + wm + mi * 16 + ((lane >> 4) << 2);
#pragma unroll
    for (int ni = 0; ni < 4; ni++) {
      int col = n0 + wn + ni * 16 + frow;
      float bv = bias[col];
      u16* op = ob + (size_t)rbase * 1024 + col;
      f32x4 a = acc[mi][ni];
#pragma unroll
      for (int i = 0; i < 4; i++) {
        float v = a[i] + bv;
        if (MODE == 1) v = v / (1.f + __expf(-v));
        if (MODE == 2) v += bf2f(op[(size_t)i * 1024]);
        op[(size_t)i * 1024] = f2bf(v);
      }
    }
  }
}

// ---------------- SSM Toeplitz dual-GEMM ----------------
// hmix[b,t,d] = (Tf@h)[t,d]*c1[b,d] + (Tb@h)[t,d]*c2[b,d]
// B-operand: Ht (B, D, L). grid: mb(16) x nb(8) x b(8)
__global__ __launch_bounds__(256) void ssm_k(
    const u16* __restrict__ Tf, const u16* __restrict__ Tb,
    const u16* __restrict__ Ht, const float* __restrict__ c1,
    const float* __restrict__ c2, u16* __restrict__ hmix) {
  __shared__ __align__(16) u16 AsF[128 * 32];
  __shared__ __align__(16) u16 AsB[128 * 32];
  __shared__ __align__(16) u16 Bs[128 * 32];
  int mb = blockIdx.x & 15, nb = (blockIdx.x >> 4) & 7, b = blockIdx.x >> 7;
  int m0 = mb * 128, n0 = nb * 128;
  const u16* Hb = Ht + (size_t)b * Dq * Lq;
  int t = threadIdx.x;
  int rr = t >> 2, cc = (t & 3) * 8;
  const u16* gaF = Tf + (size_t)(m0 + rr) * 2048 + cc;
  const u16* gaB = Tb + (size_t)(m0 + rr) * 2048 + cc;
  const u16* gb = Hb + (size_t)(n0 + rr) * 2048 + cc;
  u16* laF = &AsF[rr * 32 + cc];
  u16* laB = &AsB[rr * 32 + cc];
  u16* lb = &Bs[rr * 32 + cc];
  int lane = t & 63, w = t >> 6;
  int wm = (w >> 1) * 64, wn = (w & 1) * 64;
  int frow = lane & 15, fk = (lane >> 4) * 8;
  const u16* paF = &AsF[(wm + frow) * 32 + fk];
  const u16* paB = &AsB[(wm + frow) * 32 + fk];
  const u16* pb = &Bs[(wn + frow) * 32 + fk];
  f32x4 accf[4][4] = {};
  f32x4 accb[4][4] = {};
  for (int k0 = 0; k0 < 2048; k0 += 32) {
    bool needf = (k0 <= m0 + 127);
    bool needb = (k0 + 31 >= m0);
    if (needf) { gld16(gaF + k0, laF); gld16(gaF + k0 + 64 * 2048, laF + 64 * 32); }
    if (needb) { gld16(gaB + k0, laB); gld16(gaB + k0 + 64 * 2048, laB + 64 * 32); }
    gld16(gb + k0, lb);
    gld16(gb + k0 + 64 * 2048, lb + 64 * 32);
    asm volatile("s_waitcnt vmcnt(0)" ::: "memory");
    __syncthreads();
    bf16x8 bq[4];
#pragma unroll
    for (int i = 0; i < 4; i++) bq[i] = *(const bf16x8*)(pb + i * 512);
    if (needf) {
      bf16x8 af[4];
#pragma unroll
      for (int i = 0; i < 4; i++) af[i] = *(const bf16x8*)(paF + i * 512);
#pragma unroll
      for (int mi = 0; mi < 4; mi++)
#pragma unroll
        for (int ni = 0; ni < 4; ni++)
          accf[mi][ni] = __builtin_amdgcn_mfma_f32_16x16x32_bf16(af[mi], bq[ni], accf[mi][ni], 0, 0, 0);
    }
    if (needb) {
      bf16x8 af[4];
#pragma unroll
      for (int i = 0; i < 4; i++) af[i] = *(const bf16x8*)(paB + i * 512);
#pragma unroll
      for (int mi = 0; mi < 4; mi++)
#pragma unroll
        for (int ni = 0; ni < 4; ni++)
          accb[mi][ni] = __builtin_amdgcn_mfma_f32_16x16x32_bf16(af[mi], bq[ni], accb[mi][ni], 0, 0, 0);
    }
    __syncthreads();
  }
#pragma unroll
  for (int ni = 0; ni < 4; ni++) {
    int col = n0 + wn + ni * 16 + frow;
    float cf = c1[(b << 10) + col];
    float cb = c2[(b << 10) + col];
#pragma unroll
    for (int mi = 0; mi < 4; mi++) {
      int rbase = m0 + wm + mi * 16 + ((lane >> 4) << 2);
      u16* op = hmix + ((size_t)b * Lq + rbase) * 1024 + col;
#pragma unroll
      for (int i = 0; i < 4; i++)
        op[(size_t)i * 1024] = f2bf(accf[mi][ni][i] * cf + accb[mi][ni][i] * cb);
    }
  }
}

// ---------------- launch ----------------

extern "C" void kernel_launch(void* const* d_in, const int* in_sizes, int n_in,
                              void* d_out, int out_size, void* d_ws, size_t ws_size,
                              hipStream_t stream) {
  const float* x   = (const float*)d_in[0];
  const float* tt  = (const float*)d_in[1];
  const float* be1 = (const float*)d_in[2];
  const float* be2 = (const float*)d_in[3];
  const float* Wi  = (const float*)d_in[4];
  const float* bi  = (const float*)d_in[5];
  const float* Wo  = (const float*)d_in[6];
  const float* bo  = (const float*)d_in[7];
  const float* w1  = (const float*)d_in[8];
  const float* bc1 = (const float*)d_in[9];
  const float* w2  = (const float*)d_in[10];
  const float* bc2 = (const float*)d_in[11];
  const float* g1  = (const float*)d_in[12];
  const float* b1  = (const float*)d_in[13];
  const float* g2  = (const float*)d_in[14];
  const float* b2  = (const float*)d_in[15];
  const float* Af  = (const float*)d_in[16];
  const float* Bf  = (const float*)d_in[17];
  const float* Cf  = (const float*)d_in[18];
  const float* Df  = (const float*)d_in[19];
  const float* Ab  = (const float*)d_in[20];
  const float* Bb  = (const float*)d_in[21];
  const float* Cb  = (const float*)d_in[22];
  const float* Db  = (const float*)d_in[23];

  char* p = (char*)d_ws;
  constexpr size_t SZ_h0   = (size_t)16384 * 1024 * 2;       // 33,554,432
  constexpr size_t SZ_hpad = (size_t)Bq * LPq * Dq * 2;      // 33,587,200
  constexpr size_t SZ_ht   = (size_t)Bq * Dq * Lq * 2;       // 33,554,432
  constexpr size_t SZ_hmix = (size_t)16384 * 1024 * 2;       // 33,554,432
  constexpr size_t SZ_T    = (size_t)2048 * 2048 * 2;        // 8,388,608
  constexpr size_t SZ_wt   = (size_t)1024 * 1024 * 2;        // 2,097,152
  constexpr size_t SZ_w3t  = (size_t)1024 * 3072 * 2;        // 6,291,456

  size_t off = 0;
  u16* h0    = (u16*)(p + off); off += SZ_h0;
  u16* hpad  = (u16*)(p + off); off += SZ_hpad;
  u16* ht    = (u16*)(p + off); off += SZ_ht;
  u16* copad = (u16*)(p + off); off += SZ_hpad;
  u16* hmix  = (u16*)(p + off); off += SZ_hmix;   // overlaid: xb (dead before hmix written)
  u16* Tf    = (u16*)(p + off); off += SZ_T;
  u16* Tb    = (u16*)(p + off); off += SZ_T;
  u16* wit   = (u16*)(p + off); off += SZ_wt;
  u16* wot   = (u16*)(p + off); off += SZ_wt;
  u16* w1t   = (u16*)(p + off); off += SZ_w3t;
  u16* w2t   = (u16*)(p + off); off += SZ_w3t;
  float* kf  = (float*)(p + off); off += 8192;
  float* kb  = (float*)(p + off); off += 8192;
  float* c1  = (float*)(p + off); off += 32768;
  float* c2  = (float*)(p + off); off += 32768;
  u16* xb = hmix;  // overlay

  const long BSTR = (long)2048 * 1024;
  const long PSTR = (long)LPq * 1024;

  // prep
  prep_small<<<dim3(168), dim3(256), 0, stream>>>(tt, be1, be2, Af, Bf, Cf, Df,
                                                  Ab, Bb, Cb, Db, kf, kb, c1, c2, hpad, copad);
  cast_x<<<dim3(8192), dim3(256), 0, stream>>>(x, xb);
  trans_w<<<dim3(256), dim3(256), 0, stream>>>(Wi, wit);
  trans_w<<<dim3(256), dim3(256), 0, stream>>>(Wo, wot);
  trans_w3<<<dim3(12288), dim3(256), 0, stream>>>(w1, w1t);
  trans_w3<<<dim3(12288), dim3(256), 0, stream>>>(w2, w2t);
  tf_fill<<<dim3(16384), dim3(256), 0, stream>>>(kf, kb, Tf, Tb);

  // h0 = x @ Wi + bi (bf16)
  gemm_k<0><<<dim3(1024), dim3(256), 0, stream>>>(xb, 1024L, BSTR, wit, 1024L, h0, BSTR, bi, 1024, 128);
  // LN1 -> hpad
  ln1_k<<<dim3(16384), dim3(256), 0, stream>>>(h0, hpad, g1, b1);
  // Ht = transpose(h)
  trans_h<<<dim3(32, 16, 8), dim3(256), 0, stream>>>(hpad, ht);
  // conv1 + silu -> copad (rows 1..L)
  gemm_k<1><<<dim3(1024), dim3(256), 0, stream>>>(hpad, 1024L, PSTR, w1t, 3072L, copad + 1024, PSTR, bc1, 3072, 128);
  // SSM bidirectional Toeplitz -> hmix (partial: fwd*c1 + bwd*c2)
  ssm_k<<<dim3(1024), dim3(256), 0, stream>>>(Tf, Tb, ht, c1, c2, hmix);
  // conv2, add into hmix
  gemm_k<2><<<dim3(1024), dim3(256), 0, stream>>>(copad, 1024L, PSTR, w2t, 3072L, hmix, BSTR, bc2, 3072, 128);
  // out_pre = hmix @ Wo + bo (reuse h0 region)
  gemm_k<0><<<dim3(1024), dim3(256), 0, stream>>>(hmix, 1024L, BSTR, wot, 1024L, h0, BSTR, bo, 1024, 128);
  // out = x + LN2(out_pre)
  ln2_k<<<dim3(16384), dim3(256), 0, stream>>>(h0, x, g2, b2, (float*)d_out);
}